// Round 3
// baseline (290.882 us; speedup 1.0000x reference)
//
#include <hip/hip_runtime.h>
#include <math.h>

#define T_STEPS 32
#define BATCH 64

struct c32 { float x, y; };
__device__ inline c32 cmul(c32 a, c32 b){ return {a.x*b.x - a.y*b.y, a.x*b.y + a.y*b.x}; }
__device__ inline c32 cadd(c32 a, c32 b){ return {a.x+b.x, a.y+b.y}; }

__device__ inline float fast_sigmoid(float x){ return 1.f/(1.f + __expf(-x)); }
__device__ inline float fast_tanh(float x){ float e = __expf(2.f*x); return 1.f - 2.f/(e+1.f); }

__global__ __launch_bounds__(256)
void qlstm_kernel(const float* __restrict__ inputs,
                  const float* __restrict__ W_proj,
                  const float* __restrict__ b_proj,
                  const float* __restrict__ W_toq,
                  const float* __restrict__ W_q2h,
                  const float* __restrict__ fP, const float* __restrict__ iP,
                  const float* __restrict__ gP, const float* __restrict__ oP,
                  float* __restrict__ out)
{
    __shared__ float sTq[512];        // W_toq
    __shared__ float sFold[1024 * 8]; // [dd][q]: dd<512 -> Wxq, dd>=512 -> Whq
    __shared__ float sBq[8];
    __shared__ float sU[1024];        // 128 2x2 matrices: id = wv*32 + gl*16 + d*8 + w
    __shared__ float sKp[1024];       // kron pairs, swizzled: [(wv*2+gl)*4+p]*32 + row*8 + m*2
    __shared__ float sXq[T_STEPS * 8];
    __shared__ float sexp[4][8];
    __shared__ float qpart[4][8];

    int tid = threadIdx.x;   // 256
    int b   = blockIdx.x;    // 64
    int wv  = tid >> 6;
    int lane = tid & 63;

    // ---- init: stage W_toq, zero qpart ----
    sTq[tid] = W_toq[tid]; sTq[tid + 256] = W_toq[tid + 256];
    if (tid < 32) ((float*)qpart)[tid] = 0.f;
    __syncthreads();

    // bq
    if (tid < 8) {
        float a = 0.f;
        for (int p = 0; p < 64; ++p) a += sTq[tid * 64 + p] * b_proj[p];
        sBq[tid] = a;
    }
    // fold Wxq/Whq: out[dd][q], W_proj read once per block, coalesced
    for (int c = 0; c < 4; ++c) {
        int dd = c * 256 + tid;
        float acc[8];
        #pragma unroll
        for (int q = 0; q < 8; ++q) acc[q] = 0.f;
        for (int p = 0; p < 64; ++p) {
            float w = W_proj[p * 1024 + dd];
            #pragma unroll
            for (int q = 0; q < 8; ++q) acc[q] += sTq[q * 64 + p] * w;
        }
        #pragma unroll
        for (int q = 0; q < 8; ++q) sFold[dd * 8 + q] = acc[q];
    }
    // U matrices (threads 0..127): id = gt*32 + g*16 + d*8 + w
    if (tid < 128) {
        int gt = tid >> 5, rest = tid & 31;
        const float* P = (gt == 0) ? fP : (gt == 1) ? iP : (gt == 2) ? gP : oP;
        int g = (rest >> 4) & 1, d = (rest >> 3) & 1, w = rest & 7;
        const float* p3 = P + (((g * 2 + d) * 8 + w) * 3);
        float a = 0.5f * p3[0], bb = 0.5f * p3[1], c = 0.5f * p3[2];
        float ca = cosf(a), sa = sinf(a);
        float cb = cosf(bb), sb = sinf(bb);
        float cc = cosf(c), sc = sinf(c);
        c32 eb  = {cb, -sb};
        c32 ebc = {cb,  sb};
        c32 scx = {0.f, -sc};
        c32 m00 = { eb.x * ca,  eb.y * ca};
        c32 m01 = {-eb.x * sa, -eb.y * sa};
        c32 m10 = { ebc.x * sa, ebc.y * sa};
        c32 m11 = { ebc.x * ca, ebc.y * ca};
        c32 U00 = cadd(c32{cc * m00.x, cc * m00.y}, cmul(scx, m10));
        c32 U01 = cadd(c32{cc * m01.x, cc * m01.y}, cmul(scx, m11));
        c32 U10 = cadd(cmul(scx, m00), c32{cc * m10.x, cc * m10.y});
        c32 U11 = cadd(cmul(scx, m01), c32{cc * m11.x, cc * m11.y});
        float* dst = sU + tid * 8;
        dst[0] = U00.x; dst[1] = U00.y; dst[2] = U01.x; dst[3] = U01.y;
        dst[4] = U10.x; dst[5] = U10.y; dst[6] = U11.x; dst[7] = U11.y;
    }
    __syncthreads();

    // kron pair matrices from d=1 U's, swizzled K[row][row^m]
    for (int e = tid; e < 512; e += 256) {
        int mat = e >> 4;                 // ((wv*2+gl)*4 + p)
        int idx = e & 15;
        int row = idx >> 2, m = idx & 3, col = row ^ m;
        int pwv = mat >> 3, pgl = (mat >> 2) & 1, pp = mat & 3;
        const float* Ua = sU + (pwv * 32 + pgl * 16 + 8 + pp * 2) * 8;      // wire 2p (high bit)
        const float* Ub = sU + (pwv * 32 + pgl * 16 + 8 + pp * 2 + 1) * 8;  // wire 2p+1 (low bit)
        int i1 = row >> 1, i0 = row & 1, j1 = col >> 1, j0 = col & 1;
        c32 A  = {Ua[(i1 * 2 + j1) * 2], Ua[(i1 * 2 + j1) * 2 + 1]};
        c32 Bc = {Ub[(i0 * 2 + j0) * 2], Ub[(i0 * 2 + j0) * 2 + 1]};
        c32 K = cmul(A, Bc);
        sKp[mat * 32 + row * 8 + m * 2]     = K.x;
        sKp[mat * 32 + row * 8 + m * 2 + 1] = K.y;
    }

    // Xq for this batch: thread (t = tid>>3, q = tid&7)
    {
        int t = tid >> 3, q = tid & 7;
        const float* xr = inputs + (size_t)(t * 64 + b) * 512;
        float acc = sBq[q];
        for (int k = 0; k < 512; k += 4) {
            float4 x4 = *(const float4*)(xr + k);
            acc += x4.x * sFold[(k    ) * 8 + q] + x4.y * sFold[(k + 1) * 8 + q]
                 + x4.z * sFold[(k + 2) * 8 + q] + x4.w * sFold[(k + 3) * 8 + q];
        }
        sXq[t * 8 + q] = acc;
    }
    __syncthreads();

    // register-resident weights
    float w2h_a[8], w2h_b[8], wh_a[8], wh_b[8];
    #pragma unroll
    for (int q = 0; q < 8; ++q) {
        w2h_a[q] = W_q2h[tid * 8 + q];
        w2h_b[q] = W_q2h[(tid + 256) * 8 + q];
        wh_a[q]  = sFold[(512 + tid) * 8 + q];
        wh_b[q]  = sFold[(512 + tid + 256) * 8 + q];
    }
    float c0 = 0.f, c1 = 0.f, h0 = 0.f, h1 = 0.f;

    // Gray-map bits
    int l = lane;
    int mb0 = (l >> 5) & 1;
    int mb1 = ((l >> 4) ^ (l >> 5)) & 1;
    int mb2 = ((l >> 3) ^ (l >> 4)) & 1;
    int mb3 = ((l >> 2) ^ (l >> 3)) & 1;
    int mb4 = ((l >> 1) ^ (l >> 2)) & 1;
    int mb5 = (l ^ (l >> 1)) & 1;
    int l0 = l & 1;

    const float* sKbase = sKp + (wv * 2) * 128;  // + gl*128 inside loop

    for (int t = 0; t < T_STEPS; ++t) {
        // ---- (a) angles ----
        float ang[8];
        #pragma unroll
        for (int q = 0; q < 8; ++q)
            ang[q] = 0.5f * (sXq[t * 8 + q] + qpart[0][q] + qpart[1][q] + qpart[2][q] + qpart[3][q]);

        float e[8];
        #pragma unroll
        for (int gl = 0; gl < 2; ++gl) {
            // d=0 rotations folded with prep state
            c32 u0[8], u1[8];
            const float4* v4 = (const float4*)(sU + (wv * 4 + gl * 2) * 64);
            #pragma unroll
            for (int q = 0; q < 8; ++q) {
                float sh = __sinf(ang[q]), ch = __cosf(ang[q]);
                float4 a4 = v4[q * 2], b4 = v4[q * 2 + 1];
                u0[q].x = ch * a4.x + sh * a4.w;
                u0[q].y = ch * a4.y - sh * a4.z;
                u1[q].x = ch * b4.x + sh * b4.w;
                u1[q].y = ch * b4.y - sh * b4.z;
            }
            // d=0 CNOT chain = Gray permutation, tree product
            c32 m0 = mb0 ? u1[0] : u0[0];
            c32 m1 = mb1 ? u1[1] : u0[1];
            c32 m2 = mb2 ? u1[2] : u0[2];
            c32 m3 = mb3 ? u1[3] : u0[3];
            c32 m4 = mb4 ? u1[4] : u0[4];
            c32 m5 = mb5 ? u1[5] : u0[5];
            c32 t01 = cmul(m0, m1), t23 = cmul(m2, m3), t45 = cmul(m4, m5);
            c32 P = cmul(cmul(t01, t23), t45);
            c32 Q0 = cmul(P, l0 ? u1[6] : u0[6]);
            c32 Q1 = cmul(P, l0 ? u0[6] : u1[6]);
            c32 s[4];
            s[0] = cmul(Q0, u0[7]);
            s[1] = cmul(Q0, u1[7]);
            s[2] = cmul(Q1, u1[7]);
            s[3] = cmul(Q1, u0[7]);

            // d=1 rotations: 3 shfl kron-pair stages + 1 intra-lane
            const float* kb = sKbase + gl * 128;
            #pragma unroll
            for (int p = 0; p < 3; ++p) {
                const int shift = 4 - 2 * p;
                int myj = (lane >> shift) & 3;
                const float* kr = kb + p * 32 + myj * 8;
                float4 k01 = *(const float4*)(kr);
                float4 k23 = *(const float4*)(kr + 4);
                c32 cc0 = {k01.x, k01.y}, cc1 = {k01.z, k01.w};
                c32 cc2 = {k23.x, k23.y}, cc3 = {k23.z, k23.w};
                const int m1m = 1 << shift, m2m = 2 << shift, m3m = 3 << shift;
                #pragma unroll
                for (int r = 0; r < 4; ++r) {
                    c32 g1 = {__shfl_xor(s[r].x, m1m), __shfl_xor(s[r].y, m1m)};
                    c32 g2 = {__shfl_xor(s[r].x, m2m), __shfl_xor(s[r].y, m2m)};
                    c32 g3 = {__shfl_xor(s[r].x, m3m), __shfl_xor(s[r].y, m3m)};
                    c32 o = cmul(cc0, s[r]);
                    o = cadd(o, cmul(cc1, g1));
                    o = cadd(o, cmul(cc2, g2));
                    o = cadd(o, cmul(cc3, g3));
                    s[r] = o;
                }
            }
            {   // intra-lane pair (wires 6,7 on reg bits)
                const float* kr3 = kb + 3 * 32;
                c32 ns[4];
                #pragma unroll
                for (int r = 0; r < 4; ++r) {
                    float4 a = *(const float4*)(kr3 + r * 8);
                    float4 b2 = *(const float4*)(kr3 + r * 8 + 4);
                    c32 o = cmul(c32{a.x, a.y}, s[r]);
                    o = cadd(o, cmul(c32{a.z, a.w}, s[r ^ 1]));
                    o = cadd(o, cmul(c32{b2.x, b2.y}, s[r ^ 2]));
                    o = cadd(o, cmul(c32{b2.z, b2.w}, s[r ^ 3]));
                    ns[r] = o;
                }
                s[0] = ns[0]; s[1] = ns[1]; s[2] = ns[2]; s[3] = ns[3];
            }

            // probs + WHT (radix-4, algebraically = R2's 6-stage butterfly)
            float p0 = s[0].x * s[0].x + s[0].y * s[0].y;
            float p1 = s[1].x * s[1].x + s[1].y * s[1].y;
            float p2 = s[2].x * s[2].x + s[2].y * s[2].y;
            float p3 = s[3].x * s[3].x + s[3].y * s[3].y;
            float w0v = (p0 + p1) + (p2 + p3);
            float w6v = (p0 + p1) - (p2 + p3);
            float w7v = (p0 - p1) - (p2 - p3);
            #pragma unroll
            for (int st = 0; st < 6; st += 2) {
                int m1m = 1 << st, m2m = 2 << st, m3m = 3 << st;
                int b0 = (l >> st) & 1, b1 = (l >> (st + 1)) & 1, bx = b0 ^ b1;
                float g1, g2, g3;
                g1 = __shfl_xor(w0v, m1m); g2 = __shfl_xor(w0v, m2m); g3 = __shfl_xor(w0v, m3m);
                w0v = g3 + (b0 ? -g2 : g2) + (b1 ? -g1 : g1) + (bx ? -w0v : w0v);
                g1 = __shfl_xor(w6v, m1m); g2 = __shfl_xor(w6v, m2m); g3 = __shfl_xor(w6v, m3m);
                w6v = g3 + (b0 ? -g2 : g2) + (b1 ? -g1 : g1) + (bx ? -w6v : w6v);
                g1 = __shfl_xor(w7v, m1m); g2 = __shfl_xor(w7v, m2m); g3 = __shfl_xor(w7v, m3m);
                w7v = g3 + (b0 ? -g2 : g2) + (b1 ? -g1 : g1) + (bx ? -w7v : w7v);
            }
            e[0] = __shfl(w0v, 32); e[1] = __shfl(w0v, 48); e[2] = __shfl(w0v, 56);
            e[3] = __shfl(w0v, 60); e[4] = __shfl(w0v, 62); e[5] = __shfl(w0v, 63);
            e[6] = __shfl(w6v, 63); e[7] = __shfl(w7v, 63);
            if (gl == 0) {
                #pragma unroll
                for (int q = 0; q < 8; ++q) ang[q] = 0.5f * e[q];
            }
        }
        if (lane == 0) {
            #pragma unroll
            for (int q = 0; q < 8; ++q) sexp[wv][q] = e[q];
        }
        __syncthreads();

        // ---- LSTM cell ----
        {
            float pf0 = 0, pi0 = 0, pg0 = 0, po0 = 0, pf1 = 0, pi1 = 0, pg1 = 0, po1 = 0;
            #pragma unroll
            for (int q = 0; q < 8; ++q) {
                float e0 = sexp[0][q], e1 = sexp[1][q], e2 = sexp[2][q], e3 = sexp[3][q];
                pf0 += e0 * w2h_a[q]; pi0 += e1 * w2h_a[q]; pg0 += e2 * w2h_a[q]; po0 += e3 * w2h_a[q];
                pf1 += e0 * w2h_b[q]; pi1 += e1 * w2h_b[q]; pg1 += e2 * w2h_b[q]; po1 += e3 * w2h_b[q];
            }
            float f = fast_sigmoid(pf0), ii = fast_sigmoid(pi0);
            float g = fast_tanh(pg0),   o  = fast_sigmoid(po0);
            c0 = f * c0 + ii * g;  h0 = o * fast_tanh(c0);
            f = fast_sigmoid(pf1); ii = fast_sigmoid(pi1);
            g = fast_tanh(pg1);    o  = fast_sigmoid(po1);
            c1 = f * c1 + ii * g;  h1 = o * fast_tanh(c1);
            float* so = out + (size_t)(t * 64 + b) * 512;
            so[tid] = h0; so[tid + 256] = h1;
        }

        // ---- qpart for next step (radix reductions) ----
        {
            float part[8];
            #pragma unroll
            for (int q = 0; q < 8; ++q) part[q] = h0 * wh_a[q] + h1 * wh_b[q];
            #pragma unroll
            for (int q = 0; q < 8; ++q) {
                float t1 = __shfl_xor(part[q], 1);
                float t2 = __shfl_xor(part[q], 2);
                float t3 = __shfl_xor(part[q], 3);
                part[q] = part[q] + t1 + t2 + t3;
                part[q] += __shfl_xor(part[q], 4);
            }
            int sel = lane & 7;
            float y = sel == 0 ? part[0] : sel == 1 ? part[1] : sel == 2 ? part[2] : sel == 3 ? part[3]
                    : sel == 4 ? part[4] : sel == 5 ? part[5] : sel == 6 ? part[6] : part[7];
            float u1r = __shfl_xor(y, 8), u2r = __shfl_xor(y, 16), u3r = __shfl_xor(y, 24);
            y = y + u1r + u2r + u3r;
            y += __shfl_xor(y, 32);
            if (lane < 8) qpart[wv][lane] = y;
        }
        __syncthreads();
    }

    // final hx, cx
    float* hx_out = out + (size_t)T_STEPS * 64 * 512;
    float* cx_out = hx_out + 64 * 512;
    hx_out[b * 512 + tid]       = h0;
    hx_out[b * 512 + tid + 256] = h1;
    cx_out[b * 512 + tid]       = c0;
    cx_out[b * 512 + tid + 256] = c1;
}

extern "C" void kernel_launch(void* const* d_in, const int* in_sizes, int n_in,
                              void* d_out, int out_size, void* d_ws, size_t ws_size,
                              hipStream_t stream)
{
    const float* inputs = (const float*)d_in[0];
    const float* W_proj = (const float*)d_in[1];
    const float* b_proj = (const float*)d_in[2];
    const float* W_toq  = (const float*)d_in[3];
    const float* W_q2h  = (const float*)d_in[4];
    const float* fP     = (const float*)d_in[5];
    const float* iP     = (const float*)d_in[6];
    const float* gP     = (const float*)d_in[7];
    const float* oP     = (const float*)d_in[8];
    float* out = (float*)d_out;

    qlstm_kernel<<<BATCH, 256, 0, stream>>>(inputs, W_proj, b_proj, W_toq, W_q2h,
                                            fP, iP, gP, oP, out);
}

// Round 4
// 222.045 us; speedup vs baseline: 1.3100x; 1.3100x over previous
//
#include <hip/hip_runtime.h>
#include <math.h>

#define T_STEPS 32
#define BATCH 64

// ws layout (floats)
#define WS_WXQ 0        // [8][512]
#define WS_WHQ 4096     // [8][512]
#define WS_BQ  8192     // [8]
#define WS_U   8208     // 128 matrices * 8 floats
#define WS_XQ  9232     // [32*64][8]

struct c32 { float x, y; };
__device__ __forceinline__ c32 cmul(c32 a, c32 b){ return {a.x*b.x - a.y*b.y, a.x*b.y + a.y*b.x}; }
__device__ __forceinline__ c32 cadd(c32 a, c32 b){ return {a.x+b.x, a.y+b.y}; }

__device__ __forceinline__ float fast_sigmoid(float x){ return 1.f/(1.f + __expf(-x)); }
__device__ __forceinline__ float fast_tanh(float x){ float e = __expf(2.f*x); return 1.f - 2.f/(e+1.f); }

// DPP lane-xor helpers (VALU pipe, not LDS)
template<int C> __device__ __forceinline__ float dppf(float v){
    return __int_as_float(__builtin_amdgcn_mov_dpp(__float_as_int(v), C, 0xF, 0xF, true));
}
template<int LM> __device__ __forceinline__ float lxor(float v){
    if constexpr (LM == 1)      return dppf<0xB1>(v);                 // quad_perm {1,0,3,2}
    else if constexpr (LM == 2) return dppf<0x4E>(v);                 // quad_perm {2,3,0,1}
    else if constexpr (LM == 3) return dppf<0x1B>(v);                 // quad_perm {3,2,1,0}
    else if constexpr (LM == 4) return dppf<0x1B>(dppf<0x141>(v));    // half_mirror(xor7) o xor3
    else if constexpr (LM == 8) return dppf<0x128>(v);                // row_ror:8 == xor8 in row16
    else return __shfl_xor(v, LM);                                    // 16/32: ds pipe
}
__device__ __forceinline__ float rdl(float v, int l){
    return __int_as_float(__builtin_amdgcn_readlane(__float_as_int(v), l));
}

template<int LM>
__device__ __forceinline__ void wireX(c32 s[4], int lane, float4 a4, float4 b4){
    bool mb = (lane & LM) != 0;
    c32 ua, ub2;
    ua.x  = mb ? b4.x : a4.x;  ua.y  = mb ? b4.y : a4.y;   // mb ? U10 : U00
    ub2.x = mb ? b4.z : a4.z;  ub2.y = mb ? b4.w : a4.w;   // mb ? U11 : U01
    #pragma unroll
    for (int r = 0; r < 4; ++r) {
        float px = lxor<LM>(s[r].x);
        float py = lxor<LM>(s[r].y);
        c32 q0 = { mb ? px : s[r].x, mb ? py : s[r].y };
        c32 q1 = { mb ? s[r].x : px, mb ? s[r].y : py };
        s[r] = cadd(cmul(ua, q0), cmul(ub2, q1));
    }
}

__global__ void precompute_kernel(const float* __restrict__ W_proj,
                                  const float* __restrict__ b_proj,
                                  const float* __restrict__ W_toq,
                                  const float* __restrict__ fP, const float* __restrict__ iP,
                                  const float* __restrict__ gP, const float* __restrict__ oP,
                                  float* __restrict__ ws)
{
    int tid = threadIdx.x;
    int blk = blockIdx.x;
    if (blk < 32) {
        int idx = blk * 256 + tid;
        int q = idx >> 10, dd = idx & 1023;
        float acc = 0.f;
        for (int p = 0; p < 64; ++p) acc += W_toq[q * 64 + p] * W_proj[p * 1024 + dd];
        if (dd < 512) ws[WS_WXQ + q * 512 + dd] = acc;
        else          ws[WS_WHQ + q * 512 + (dd - 512)] = acc;
        if (idx < 8) {
            float a2 = 0.f;
            for (int p = 0; p < 64; ++p) a2 += W_toq[idx * 64 + p] * b_proj[p];
            ws[WS_BQ + idx] = a2;
        }
    } else if (tid < 128) {
        int gt = tid >> 5, rest = tid & 31;
        const float* P = (gt == 0) ? fP : (gt == 1) ? iP : (gt == 2) ? gP : oP;
        int g = (rest >> 4) & 1, d = (rest >> 3) & 1, w = rest & 7;
        const float* p3 = P + (((g * 2 + d) * 8 + w) * 3);
        float a = 0.5f * p3[0], b = 0.5f * p3[1], c = 0.5f * p3[2];
        float ca = cosf(a), sa = sinf(a);
        float cb = cosf(b), sb = sinf(b);
        float cc = cosf(c), sc = sinf(c);
        c32 eb  = {cb, -sb};
        c32 ebc = {cb,  sb};
        c32 scx = {0.f, -sc};
        c32 m00 = { eb.x * ca,  eb.y * ca};
        c32 m01 = {-eb.x * sa, -eb.y * sa};
        c32 m10 = { ebc.x * sa, ebc.y * sa};
        c32 m11 = { ebc.x * ca, ebc.y * ca};
        c32 U00 = cadd(c32{cc * m00.x, cc * m00.y}, cmul(scx, m10));
        c32 U01 = cadd(c32{cc * m01.x, cc * m01.y}, cmul(scx, m11));
        c32 U10 = cadd(cmul(scx, m00), c32{cc * m10.x, cc * m10.y});
        c32 U11 = cadd(cmul(scx, m01), c32{cc * m11.x, cc * m11.y});
        float* dst = ws + WS_U + tid * 8;
        dst[0] = U00.x; dst[1] = U00.y; dst[2] = U01.x; dst[3] = U01.y;
        dst[4] = U10.x; dst[5] = U10.y; dst[6] = U11.x; dst[7] = U11.y;
    }
}

__global__ void xq_kernel(const float* __restrict__ inputs, float* __restrict__ ws)
{
    __shared__ float xs[512];
    int row = blockIdx.x;           // t*64 + b
    int tid = threadIdx.x;          // 256
    xs[tid]       = inputs[row * 512 + tid];
    xs[tid + 256] = inputs[row * 512 + 256 + tid];
    __syncthreads();
    int g = tid >> 5, j = tid & 31;
    const float* w = ws + WS_WXQ + g * 512;
    float acc = 0.f;
    #pragma unroll 4
    for (int i = 0; i < 16; ++i) acc += xs[j + 32 * i] * w[j + 32 * i];
    acc += __shfl_xor(acc, 1);  acc += __shfl_xor(acc, 2);
    acc += __shfl_xor(acc, 4);  acc += __shfl_xor(acc, 8);
    acc += __shfl_xor(acc, 16);
    if (j == 0) ws[WS_XQ + row * 8 + g] = acc + ws[WS_BQ + g];
}

__global__ __launch_bounds__(256, 1)
void recurrence_kernel(const float* __restrict__ W_q2h,
                       const float* __restrict__ ws,
                       float* __restrict__ out)
{
    __shared__ __align__(16) float sU[1024];
    __shared__ __align__(16) float sXq[T_STEPS * 8];
    __shared__ __align__(16) float sexpT[8][4];   // [q][gate]
    __shared__ __align__(16) float qpart4[8][4];  // [q][gate]

    int tid = threadIdx.x;   // 256
    int b   = blockIdx.x;    // 64
    int wv  = tid >> 6;
    int lane = tid & 63;
    int l = lane;

    for (int i = tid; i < 1024; i += 256) sU[i] = ws[WS_U + i];
    sXq[tid] = ws[WS_XQ + ((tid >> 3) * 64 + b) * 8 + (tid & 7)];
    if (tid < 32) ((float*)qpart4)[tid] = 0.f;

    // d=1 matrices in registers (critical chain), per-wave
    float4 m1[2][8][2];
    {
        const float4* Ub4 = (const float4*)(ws + WS_U);
        #pragma unroll
        for (int gl = 0; gl < 2; ++gl)
            #pragma unroll
            for (int w = 0; w < 8; ++w) {
                m1[gl][w][0] = Ub4[(wv * 32 + gl * 16 + 8 + w) * 2];
                m1[gl][w][1] = Ub4[(wv * 32 + gl * 16 + 8 + w) * 2 + 1];
            }
    }
    // register-resident weights
    float w2h_a[8], w2h_b[8], wh_a[8], wh_b[8];
    #pragma unroll
    for (int q = 0; q < 8; ++q) {
        w2h_a[q] = W_q2h[tid * 8 + q];
        w2h_b[q] = W_q2h[(tid + 256) * 8 + q];
        wh_a[q]  = ws[WS_WHQ + q * 512 + tid];
        wh_b[q]  = ws[WS_WHQ + q * 512 + tid + 256];
    }
    float c0 = 0.f, c1 = 0.f, h0 = 0.f, h1 = 0.f;

    // Gray-map bits
    int mb0 = (l >> 5) & 1;
    int mb1 = ((l >> 4) ^ (l >> 5)) & 1;
    int mb2 = ((l >> 3) ^ (l >> 4)) & 1;
    int mb3 = ((l >> 2) ^ (l >> 3)) & 1;
    int mb4 = ((l >> 1) ^ (l >> 2)) & 1;
    int mb5 = (l ^ (l >> 1)) & 1;
    int l0 = l & 1;

    __syncthreads();

    for (int t = 0; t < T_STEPS; ++t) {
        // ---- (a) angles: Xq + 4 gate partials (vector LDS reads) ----
        float ang[8];
        {
            float4 x0 = *(const float4*)&sXq[t * 8];
            float4 x1 = *(const float4*)&sXq[t * 8 + 4];
            float xv[8] = {x0.x, x0.y, x0.z, x0.w, x1.x, x1.y, x1.z, x1.w};
            #pragma unroll
            for (int q = 0; q < 8; ++q) {
                float4 qp = *(const float4*)&qpart4[q][0];
                ang[q] = 0.5f * (xv[q] + ((qp.x + qp.y) + (qp.z + qp.w)));
            }
        }

        float e[8];
        #pragma unroll
        for (int gl = 0; gl < 2; ++gl) {
            // d=0 rotations folded with |0..0> prep (product state)
            c32 u0[8], u1[8];
            const float4* v4 = (const float4*)(sU + (wv * 4 + gl * 2) * 64);
            #pragma unroll
            for (int q = 0; q < 8; ++q) {
                float sh = __sinf(ang[q]), ch = __cosf(ang[q]);
                float4 a4 = v4[q * 2], b4 = v4[q * 2 + 1];
                u0[q].x = ch * a4.x + sh * a4.w;
                u0[q].y = ch * a4.y - sh * a4.z;
                u1[q].x = ch * b4.x + sh * b4.w;
                u1[q].y = ch * b4.y - sh * b4.z;
            }
            // d=0 CNOT chain = Gray permutation, tree product
            c32 m0 = mb0 ? u1[0] : u0[0];
            c32 mm1 = mb1 ? u1[1] : u0[1];
            c32 m2 = mb2 ? u1[2] : u0[2];
            c32 m3 = mb3 ? u1[3] : u0[3];
            c32 m4 = mb4 ? u1[4] : u0[4];
            c32 m5 = mb5 ? u1[5] : u0[5];
            c32 t01 = cmul(m0, mm1), t23 = cmul(m2, m3), t45 = cmul(m4, m5);
            c32 P = cmul(cmul(t01, t23), t45);
            c32 Q0 = cmul(P, l0 ? u1[6] : u0[6]);
            c32 Q1 = cmul(P, l0 ? u0[6] : u1[6]);
            c32 s[4];
            s[0] = cmul(Q0, u0[7]);
            s[1] = cmul(Q0, u1[7]);
            s[2] = cmul(Q1, u1[7]);
            s[3] = cmul(Q1, u0[7]);

            // d=1 rotations: cross-lane wires (DPP for 1/2/4/8, ds for 16/32)
            wireX<32>(s, lane, m1[gl][0][0], m1[gl][0][1]);
            wireX<16>(s, lane, m1[gl][1][0], m1[gl][1][1]);
            wireX<8> (s, lane, m1[gl][2][0], m1[gl][2][1]);
            wireX<4> (s, lane, m1[gl][3][0], m1[gl][3][1]);
            wireX<2> (s, lane, m1[gl][4][0], m1[gl][4][1]);
            wireX<1> (s, lane, m1[gl][5][0], m1[gl][5][1]);
            {   // jb==1: pairs (r0,r2),(r1,r3)
                float4 a4 = m1[gl][6][0], b4 = m1[gl][6][1];
                c32 u00 = {a4.x, a4.y}, u01 = {a4.z, a4.w};
                c32 u10 = {b4.x, b4.y}, u11 = {b4.z, b4.w};
                c32 a0 = s[0], b0 = s[2], a1 = s[1], b1 = s[3];
                s[0] = cadd(cmul(u00, a0), cmul(u01, b0));
                s[2] = cadd(cmul(u10, a0), cmul(u11, b0));
                s[1] = cadd(cmul(u00, a1), cmul(u01, b1));
                s[3] = cadd(cmul(u10, a1), cmul(u11, b1));
            }
            {   // jb==0: pairs (r0,r1),(r2,r3)
                float4 a4 = m1[gl][7][0], b4 = m1[gl][7][1];
                c32 u00 = {a4.x, a4.y}, u01 = {a4.z, a4.w};
                c32 u10 = {b4.x, b4.y}, u11 = {b4.z, b4.w};
                c32 a0 = s[0], b0 = s[1], a1 = s[2], b1 = s[3];
                s[0] = cadd(cmul(u00, a0), cmul(u01, b0));
                s[1] = cadd(cmul(u10, a0), cmul(u11, b0));
                s[2] = cadd(cmul(u00, a1), cmul(u01, b1));
                s[3] = cadd(cmul(u10, a1), cmul(u11, b1));
            }

            // probs + WHT butterfly (d=1 CNOT folded into parity signs)
            float p0 = s[0].x * s[0].x + s[0].y * s[0].y;
            float p1 = s[1].x * s[1].x + s[1].y * s[1].y;
            float p2 = s[2].x * s[2].x + s[2].y * s[2].y;
            float p3 = s[3].x * s[3].x + s[3].y * s[3].y;
            float w0v = (p0 + p1) + (p2 + p3);
            float w6v = (p0 + p1) - (p2 + p3);
            float w7v = (p0 - p1) - (p2 - p3);
            #define WHT_STAGE(M, SH) { int bit = (l >> SH) & 1; float v; \
                v = lxor<M>(w0v); w0v = bit ? v - w0v : v + w0v; \
                v = lxor<M>(w6v); w6v = bit ? v - w6v : v + w6v; \
                v = lxor<M>(w7v); w7v = bit ? v - w7v : v + w7v; }
            WHT_STAGE(1, 0) WHT_STAGE(2, 1) WHT_STAGE(4, 2)
            WHT_STAGE(8, 3) WHT_STAGE(16, 4) WHT_STAGE(32, 5)
            #undef WHT_STAGE
            e[0] = rdl(w0v, 32); e[1] = rdl(w0v, 48); e[2] = rdl(w0v, 56);
            e[3] = rdl(w0v, 60); e[4] = rdl(w0v, 62); e[5] = rdl(w0v, 63);
            e[6] = rdl(w6v, 63); e[7] = rdl(w7v, 63);
            if (gl == 0) {
                #pragma unroll
                for (int q = 0; q < 8; ++q) ang[q] = 0.5f * e[q];
            }
        }
        if (lane == 0) {
            #pragma unroll
            for (int q = 0; q < 8; ++q) sexpT[q][wv] = e[q];
        }
        __syncthreads();

        // ---- LSTM cell, 2 h per thread, weights in registers ----
        {
            float pf0 = 0, pi0 = 0, pg0 = 0, po0 = 0, pf1 = 0, pi1 = 0, pg1 = 0, po1 = 0;
            #pragma unroll
            for (int q = 0; q < 8; ++q) {
                float4 ee = *(const float4*)&sexpT[q][0];
                pf0 += ee.x * w2h_a[q]; pi0 += ee.y * w2h_a[q];
                pg0 += ee.z * w2h_a[q]; po0 += ee.w * w2h_a[q];
                pf1 += ee.x * w2h_b[q]; pi1 += ee.y * w2h_b[q];
                pg1 += ee.z * w2h_b[q]; po1 += ee.w * w2h_b[q];
            }
            float f = fast_sigmoid(pf0), ii = fast_sigmoid(pi0);
            float g = fast_tanh(pg0),   o  = fast_sigmoid(po0);
            c0 = f * c0 + ii * g;  h0 = o * fast_tanh(c0);
            f = fast_sigmoid(pf1); ii = fast_sigmoid(pi1);
            g = fast_tanh(pg1);    o  = fast_sigmoid(po1);
            c1 = f * c1 + ii * g;  h1 = o * fast_tanh(c1);
            float* so = out + (size_t)(t * 64 + b) * 512;
            so[tid] = h0; so[tid + 256] = h1;
        }

        // ---- qpart for next step (DPP-heavy reductions) ----
        {
            float part[8];
            #pragma unroll
            for (int q = 0; q < 8; ++q) part[q] = h0 * wh_a[q] + h1 * wh_b[q];
            #pragma unroll
            for (int q = 0; q < 8; ++q) {
                part[q] += lxor<1>(part[q]);
                part[q] += lxor<2>(part[q]);
                part[q] += lxor<4>(part[q]);
            }
            int sel = lane & 7;
            float y = sel == 0 ? part[0] : sel == 1 ? part[1] : sel == 2 ? part[2] : sel == 3 ? part[3]
                    : sel == 4 ? part[4] : sel == 5 ? part[5] : sel == 6 ? part[6] : part[7];
            y += lxor<8>(y);
            y += __shfl_xor(y, 16);
            y += __shfl_xor(y, 32);
            if (lane < 8) qpart4[lane][wv] = y;
        }
        __syncthreads();
    }

    // final hx, cx from registers
    float* hx_out = out + (size_t)T_STEPS * 64 * 512;
    float* cx_out = hx_out + 64 * 512;
    hx_out[b * 512 + tid]       = h0;
    hx_out[b * 512 + tid + 256] = h1;
    cx_out[b * 512 + tid]       = c0;
    cx_out[b * 512 + tid + 256] = c1;
}

extern "C" void kernel_launch(void* const* d_in, const int* in_sizes, int n_in,
                              void* d_out, int out_size, void* d_ws, size_t ws_size,
                              hipStream_t stream)
{
    const float* inputs = (const float*)d_in[0];
    const float* W_proj = (const float*)d_in[1];
    const float* b_proj = (const float*)d_in[2];
    const float* W_toq  = (const float*)d_in[3];
    const float* W_q2h  = (const float*)d_in[4];
    const float* fP     = (const float*)d_in[5];
    const float* iP     = (const float*)d_in[6];
    const float* gP     = (const float*)d_in[7];
    const float* oP     = (const float*)d_in[8];
    float* ws  = (float*)d_ws;
    float* out = (float*)d_out;

    precompute_kernel<<<33, 256, 0, stream>>>(W_proj, b_proj, W_toq, fP, iP, gP, oP, ws);
    xq_kernel<<<T_STEPS * BATCH, 256, 0, stream>>>(inputs, ws);
    recurrence_kernel<<<BATCH, 256, 0, stream>>>(W_q2h, ws, out);
}